// Round 12
// baseline (304.384 us; speedup 1.0000x reference)
//
#include <hip/hip_runtime.h>

#define NN 100000
#define NE 1600000
#define FIN 64
#define FOUT 7

#define BSH 9                         // bucket = dst >> 9 (512 nodes)
#define NBK 196                       // ceil(100000/512)
#define NREG 2000                     // regions (2000*800 = NE exact)
#define EPB  800                      // edges per region
#define ROWS 200                      // offs row stride (u16, 197 used)
#define NCOPY 4                       // counter copies (wave&3)
#define NCTR (NBK * NCOPY)            // 784
#define SPLIT 4                       // acc splits per bucket
#define NTASK (NBK * SPLIT)           // 784 acc tasks
#define RPS (NREG / SPLIT)            // 500 regions per task
#define CAPR 8                        // register-held edges/region (mean 4.08)
#define OVCAP 256                     // LDS overflow pairs (expect ~12)
#define SCAP 2560                     // per-task stage cap (mean 2040, +11 sigma)
#define BLKS 256                      // persistent grid: 1 block per CU
#define TH 1024
#define INVALID 0xFFFFFFFFu

__device__ __forceinline__ unsigned bf16r(float f) {   // round-to-nearest-even
    unsigned u = __float_as_uint(f);
    return (u + 0x7fffu + ((u >> 16) & 1u)) >> 16;
}
__device__ __forceinline__ float bflo(unsigned u) { return __uint_as_float(u << 16); }
__device__ __forceinline__ float bfhi(unsigned u) { return __uint_as_float(u & 0xffff0000u); }

// Device-scope generation barrier. Safe because grid = 256 blocks = #CUs:
// every block is resident before any can arrive, so no block waits on an
// undispatched one. cnt/gen live in d_ws (zeroed via tiny memsetAsync).
__device__ __forceinline__ void gbarrier(int* cnt, int* gen) {
    __syncthreads();
    if (threadIdx.x == 0) {
        int g = __hip_atomic_load(gen, __ATOMIC_ACQUIRE, __HIP_MEMORY_SCOPE_AGENT);
        int a = __hip_atomic_fetch_add(cnt, 1, __ATOMIC_ACQ_REL, __HIP_MEMORY_SCOPE_AGENT);
        if (a == BLKS - 1) {
            __hip_atomic_store(cnt, 0, __ATOMIC_RELAXED, __HIP_MEMORY_SCOPE_AGENT);
            __hip_atomic_fetch_add(gen, 1, __ATOMIC_ACQ_REL, __HIP_MEMORY_SCOPE_AGENT);
        } else {
            while (__hip_atomic_load(gen, __ATOMIC_ACQUIRE, __HIP_MEMORY_SCOPE_AGENT) == g)
                __builtin_amdgcn_s_sleep(2);
        }
    }
    __syncthreads();
}

// ---------------------------------------------------------------------------
// Persistent mega-kernel: proj ∥ part -> gbarrier -> acc -> gbarrier -> merge.
// All internals are the R9/R10-proven versions; only dispatch structure changes.
// ---------------------------------------------------------------------------
__global__ __launch_bounds__(TH) void mega_kernel(
    const int* __restrict__ eg, const float* __restrict__ x,
    const float* __restrict__ Wl, const float* __restrict__ bl,
    const float* __restrict__ Wr, unsigned* __restrict__ z,
    unsigned* __restrict__ part, unsigned short* __restrict__ offs,
    float* __restrict__ partial, float* __restrict__ out, int* __restrict__ bar)
{
    __shared__ unsigned s_cnt[NCTR];      // part: 784 ctrs | acc: 512 node cnts
    __shared__ unsigned s_start[NCTR];
    __shared__ unsigned sstage[SCAP];     // part: stage[800] | acc: node-sorted srcs
    __shared__ unsigned ovf[2 * OVCAP];
    __shared__ unsigned novf;
    __shared__ unsigned wtot[16];

    const int t    = threadIdx.x;
    const int lane = t & 63;

    // ===== phase 1a: proj (blocks with i>=NN fall through into part) =====
    {
        int i = (int)blockIdx.x * TH + t;      // 262144 threads cover NN once
        if (i < NN) {
            float al[FOUT], ar[FOUT];
#pragma unroll
            for (int j = 0; j < FOUT; ++j) { al[j] = 0.f; ar[j] = 0.f; }
            const float4* xr = (const float4*)(x + (size_t)i * FIN);
#pragma unroll
            for (int kk = 0; kk < FIN / 4; ++kk) {
                float4 xv = xr[kk];
                float v[4] = {xv.x, xv.y, xv.z, xv.w};
#pragma unroll
                for (int c = 0; c < 4; ++c) {
                    int k = kk * 4 + c;
#pragma unroll
                    for (int j = 0; j < FOUT; ++j) {
                        al[j] = fmaf(v[c], Wl[k * FOUT + j], al[j]);  // uniform -> s_load
                        ar[j] = fmaf(v[c], Wr[k * FOUT + j], ar[j]);
                    }
                }
            }
            uint4 pk;
            pk.x = bf16r(al[0]) | (bf16r(al[1]) << 16);
            pk.y = bf16r(al[2]) | (bf16r(al[3]) << 16);
            pk.z = bf16r(al[4]) | (bf16r(al[5]) << 16);
            pk.w = bf16r(al[6]);
            ((uint4*)z)[i] = pk;
            float* o = out + (size_t)i * FOUT;
#pragma unroll
            for (int j = 0; j < FOUT; ++j) o[j] = ar[j] + bl[j];
        }
    }

    // ===== phase 1b: partition (grid-stride over 2000 regions) =====
    for (int r = blockIdx.x; r < NREG; r += BLKS) {
        for (int i = t; i < NCTR; i += TH) s_cnt[i] = 0;
        __syncthreads();

        unsigned held = 0, hcr = INVALID;
        if (t < EPB) {
            unsigned s = (unsigned)eg[r * EPB + t];
            unsigned d = (unsigned)eg[NE + r * EPB + t];
            unsigned cidx = (d >> BSH) * NCOPY + ((t >> 6) & 3);
            unsigned rk = atomicAdd(&s_cnt[cidx], 1u);
            held = ((d & 511u) << 17) | s;         // ldst 9b | src 17b
            hcr  = (cidx << 10) | rk;              // cidx 10b | rk<800 10b
        }
        __syncthreads();

        // pair shfl-scan of 784 counters (threads 0..511 = 8 waves)
        unsigned c0 = 0, c1 = 0, p = 0, inc = 0;
        if (t < 512) {
            unsigned i0 = 2 * t, i1 = 2 * t + 1;
            c0 = (i0 < NCTR) ? s_cnt[i0] : 0u;
            c1 = (i1 < NCTR) ? s_cnt[i1] : 0u;
            p = c0 + c1; inc = p;
#pragma unroll
            for (int off = 1; off < 64; off <<= 1) {
                unsigned v = (unsigned)__shfl_up((int)inc, off, 64);
                if (lane >= off) inc += v;
            }
            if (lane == 63) wtot[t >> 6] = inc;
        }
        __syncthreads();
        if (t == 0) {
            unsigned run = 0;
#pragma unroll
            for (int w = 0; w < 8; ++w) { unsigned tmp = wtot[w]; wtot[w] = run; run += tmp; }
        }
        __syncthreads();
        if (t < 512) {
            unsigned base = wtot[t >> 6] + inc - p;
            unsigned i0 = 2 * t, i1 = 2 * t + 1;
            if (i0 < NCTR) s_start[i0] = base;
            if (i1 < NCTR) s_start[i1] = base + c0;
        }
        __syncthreads();

        if (t <= NBK)
            offs[(size_t)r * ROWS + t] =
                (unsigned short)((t == NBK) ? EPB : s_start[t * NCOPY]);
        if (hcr != INVALID)
            sstage[s_start[hcr >> 10] + (hcr & 1023u)] = held;
        __syncthreads();

        uint4* pg = (uint4*)(part + (size_t)r * EPB);
        if (t < EPB / 4) pg[t] = ((const uint4*)sstage)[t];
        __syncthreads();
    }

    gbarrier(bar, bar + 16);

    // ===== phase 2: accumulate (grid-stride over 784 bucket-split tasks) =====
    for (int task = blockIdx.x; task < NTASK; task += BLKS) {
        const int k  = task >> 2;
        const int sp = task & 3;

        if (t < 512) s_cnt[t] = 0;
        if (t == 0) novf = 0;
        __syncthreads();

        unsigned rbase = 0, len = 0;
        if (t < RPS) {
            unsigned r = (unsigned)(sp * RPS + t);
            unsigned o0 = offs[(size_t)r * ROWS + k];
            unsigned o1 = offs[(size_t)r * ROWS + k + 1];
            len   = o1 - o0;
            rbase = r * EPB + o0;
        }

        // pass A: single read of my run; merged hist+rank; hold in registers
        unsigned hsrc[CAPR], hnr[CAPR];
#pragma unroll
        for (int j = 0; j < CAPR; ++j) {
            if (j < (int)len) {
                unsigned e = part[rbase + j];
                unsigned node = e >> 17;
                unsigned rk = atomicAdd(&s_cnt[node], 1u);
                hsrc[j] = e & 0x1FFFFu;
                hnr[j]  = (node << 16) | rk;
            } else hnr[j] = INVALID;
        }
        for (int j = CAPR; j < (int)len; ++j) {      // rare tail
            unsigned e = part[rbase + j];
            unsigned node = e >> 17;
            unsigned rk = atomicAdd(&s_cnt[node], 1u);
            unsigned pp = atomicAdd(&novf, 1u);
            if (pp < OVCAP) {
                ovf[2 * pp]     = (node << 16) | rk;
                ovf[2 * pp + 1] = e & 0x1FFFFu;
            }
        }
        __syncthreads();

        // shfl-scan of 512 node counts
        unsigned cval = 0, inc = 0;
        if (t < 512) {
            cval = s_cnt[t]; inc = cval;
#pragma unroll
            for (int off = 1; off < 64; off <<= 1) {
                unsigned v = (unsigned)__shfl_up((int)inc, off, 64);
                if (lane >= off) inc += v;
            }
            if (lane == 63) wtot[t >> 6] = inc;
        }
        __syncthreads();
        if (t == 0) {
            unsigned run = 0;
#pragma unroll
            for (int w = 0; w < 8; ++w) { unsigned tmp = wtot[w]; wtot[w] = run; run += tmp; }
        }
        __syncthreads();
        if (t < 512) s_start[t] = wtot[t >> 6] + inc - cval;
        __syncthreads();

        // pass B: scatter from registers (+ overflow) into node-sorted stage
#pragma unroll
        for (int j = 0; j < CAPR; ++j) {
            if (hnr[j] != INVALID) {
                unsigned node = hnr[j] >> 16, rk = hnr[j] & 0xffffu;
                unsigned pp = s_start[node] + rk;
                if (pp < SCAP) sstage[pp] = hsrc[j];
            }
        }
        for (unsigned q = t; q < min(novf, (unsigned)OVCAP); q += TH) {
            unsigned nr = ovf[2 * q], src = ovf[2 * q + 1];
            unsigned pp = s_start[nr >> 16] + (nr & 0xffffu);
            if (pp < SCAP) sstage[pp] = src;
        }
        __syncthreads();

        // pass C: thread t reduces node t's run (mean deg ~4), dumps partial
        if (t < 512) {
            unsigned deg  = s_cnt[t];
            unsigned base = s_start[t];
            unsigned hi   = min(base + deg, (unsigned)SCAP);
            float a0 = 0.f, a1 = 0.f, a2 = 0.f, a3 = 0.f, a4 = 0.f, a5 = 0.f, a6 = 0.f;
            for (unsigned j = base; j < hi; ++j) {
                uint4 zr = ((const uint4*)z)[sstage[j]];
                a0 += bflo(zr.x); a1 += bfhi(zr.x);
                a2 += bflo(zr.y); a3 += bfhi(zr.y);
                a4 += bflo(zr.z); a5 += bfhi(zr.z);
                a6 += bflo(zr.w);
            }
            float* pp = partial + ((size_t)task * 512 + t) * 8;
            *(float4*)(pp)     = make_float4(a0, a1, a2, a3);
            *(float4*)(pp + 4) = make_float4(a4, a5, a6, (float)deg);
        }
        __syncthreads();
    }

    gbarrier(bar, bar + 16);

    // ===== phase 3: merge 4 split partials + mean + self + relu =====
    {
        int i = (int)blockIdx.x * TH + t;
        if (i < NN) {
            int k = i >> BSH, node = i & 511;
            float s0 = 0.f, s1 = 0.f, s2 = 0.f, s3 = 0.f,
                  s4 = 0.f, s5 = 0.f, s6 = 0.f, cn = 0.f;
#pragma unroll
            for (int sp = 0; sp < SPLIT; ++sp) {
                const float4* p =
                    (const float4*)(partial + ((size_t)(k * SPLIT + sp) * 512 + node) * 8);
                float4 a = p[0], b = p[1];
                s0 += a.x; s1 += a.y; s2 += a.z; s3 += a.w;
                s4 += b.x; s5 += b.y; s6 += b.z; cn += b.w;
            }
            float r = 1.0f / fmaxf(cn, 1.0f);
            float* o = out + (size_t)i * FOUT;
            o[0] = fmaxf(fmaf(s0, r, o[0]), 0.f);
            o[1] = fmaxf(fmaf(s1, r, o[1]), 0.f);
            o[2] = fmaxf(fmaf(s2, r, o[2]), 0.f);
            o[3] = fmaxf(fmaf(s3, r, o[3]), 0.f);
            o[4] = fmaxf(fmaf(s4, r, o[4]), 0.f);
            o[5] = fmaxf(fmaf(s5, r, o[5]), 0.f);
            o[6] = fmaxf(fmaf(s6, r, o[6]), 0.f);
        }
    }
}

extern "C" void kernel_launch(void* const* d_in, const int* in_sizes, int n_in,
                              void* d_out, int out_size, void* d_ws, size_t ws_size,
                              hipStream_t stream) {
    const float* x   = (const float*)d_in[0];
    const int*   edg = (const int*)d_in[1];    // harness passes integers as int32
    const float* Wl  = (const float*)d_in[2];
    const float* bl  = (const float*)d_in[3];
    const float* Wr  = (const float*)d_in[4];
    float* out = (float*)d_out;

    // ws: z 1.6 MB | part 6.4 MB | offs 0.8 MB | partial 12.8 MB | barrier 128 B
    unsigned*       z       = (unsigned*)d_ws;                            // [NN*4]
    unsigned*       part    = z + (size_t)NN * 4;                         // [NE]
    unsigned short* offs    = (unsigned short*)(part + (size_t)NE);      // [NREG*ROWS]
    float*          partial = (float*)(offs + (size_t)NREG * ROWS);      // [NTASK*512*8]
    int*            bar     = (int*)(partial + (size_t)NTASK * 512 * 8); // [32]

    hipMemsetAsync(bar, 0, 32 * sizeof(int), stream);   // cnt @0, gen @16

    mega_kernel<<<BLKS, TH, 0, stream>>>(edg, x, Wl, bl, Wr,
                                         z, part, offs, partial, out, bar);
}

// Round 14
// 123.383 us; speedup vs baseline: 2.4670x; 2.4670x over previous
//
#include <hip/hip_runtime.h>

#define NN 100000
#define NE 1600000
#define FIN 64
#define FOUT 7

#define BSH 9                        // bucket = dst >> 9 (512 nodes)
#define NBK 196                      // ceil(100000/512)
#define PBLK 2000                    // partition blocks (2000*800 = NE exact)
#define PTH  256
#define EPB  800                     // edges per partition region
#define EPT  4                       // ceil(800/256) register slots
#define NCOPY 4                      // per-wave counter copies (4 waves)
#define NCTR (NBK * NCOPY)           // 784
#define ROWS 200                     // offs row stride in u16 (197 used)
#define SPLIT 4                      // acc blocks per bucket
#define NTASK (NBK * SPLIT)          // 784
#define RPS (PBLK / SPLIT)           // 500 regions per acc task
#define ATH 512
#define WSLOT 12                     // aligned uint4 window: 3 x dwordx4
#define OVCAP 256                    // LDS overflow pairs (expect ~20/task)
#define SCAP 3968                    // padded stage cap (edges<=2250 + align pad 1536)
#define PROJB 391
#define INVALID 0xFFFFFFFFu

__device__ __forceinline__ unsigned bf16r(float f) {   // round-to-nearest-even
    unsigned u = __float_as_uint(f);
    return (u + 0x7fffu + ((u >> 16) & 1u)) >> 16;
}
__device__ __forceinline__ float bflo(unsigned u) { return __uint_as_float(u << 16); }
__device__ __forceinline__ float bfhi(unsigned u) { return __uint_as_float(u & 0xffff0000u); }

// ---------------------------------------------------------------------------
// Kernel 1: per-node projections (R10-identical).
// ---------------------------------------------------------------------------
__global__ __launch_bounds__(256) void proj_kernel(
    const float* __restrict__ x, const float* __restrict__ Wl,
    const float* __restrict__ bl, const float* __restrict__ Wr,
    unsigned* __restrict__ z, float* __restrict__ outself, int n)
{
    int i = blockIdx.x * blockDim.x + threadIdx.x;
    if (i >= n) return;

    float al[FOUT], ar[FOUT];
#pragma unroll
    for (int j = 0; j < FOUT; ++j) { al[j] = 0.f; ar[j] = 0.f; }

    const float4* xr = (const float4*)(x + (size_t)i * FIN);
#pragma unroll
    for (int kk = 0; kk < FIN / 4; ++kk) {
        float4 xv = xr[kk];
        float v[4] = {xv.x, xv.y, xv.z, xv.w};
#pragma unroll
        for (int c = 0; c < 4; ++c) {
            int k = kk * 4 + c;
#pragma unroll
            for (int j = 0; j < FOUT; ++j) {
                al[j] = fmaf(v[c], Wl[k * FOUT + j], al[j]);   // uniform -> s_load
                ar[j] = fmaf(v[c], Wr[k * FOUT + j], ar[j]);
            }
        }
    }

    uint4 pk;
    pk.x = bf16r(al[0]) | (bf16r(al[1]) << 16);
    pk.y = bf16r(al[2]) | (bf16r(al[3]) << 16);
    pk.z = bf16r(al[4]) | (bf16r(al[5]) << 16);
    pk.w = bf16r(al[6]);
    ((uint4*)z)[i] = pk;

    float* o = outself + (size_t)i * FOUT;
#pragma unroll
    for (int j = 0; j < FOUT; ++j)
        o[j] = ar[j] + bl[j];
}

// ---------------------------------------------------------------------------
// Kernel 2: partition (R10-identical: merged hist+rank, LDS stage, linear
// uint4 region dump — the best-measured part variant).
// ---------------------------------------------------------------------------
__global__ __launch_bounds__(PTH) void part_kernel(
    const int* __restrict__ eg, unsigned* __restrict__ part,
    unsigned short* __restrict__ offs)
{
    __shared__ unsigned st_cnt[NCTR];
    __shared__ unsigned st_start[NCTR];
    __shared__ unsigned stage[EPB];
    __shared__ unsigned wsum[NCOPY];

    const int t    = threadIdx.x;
    const int e0   = (int)blockIdx.x * EPB;
    const int lane = t & 63;
    const int wv   = t >> 6;

    for (int b = t; b < NCTR; b += PTH) st_cnt[b] = 0;
    __syncthreads();

    unsigned held[EPT], hcr[EPT];
#pragma unroll
    for (int j = 0; j < EPT; ++j) {
        int k = t + j * PTH;
        if (k < EPB) {
            unsigned s = (unsigned)eg[e0 + k];
            unsigned d = (unsigned)eg[NE + e0 + k];
            unsigned cidx = (d >> BSH) * NCOPY + wv;
            unsigned r = atomicAdd(&st_cnt[cidx], 1u);
            held[j] = ((d & 511u) << 17) | s;      // ldst 9b | src 17b
            hcr[j]  = (cidx << 10) | r;            // cidx 10b | r<800 10b
        } else hcr[j] = INVALID;
    }
    __syncthreads();

    {
        unsigned c[4], sum = 0;
#pragma unroll
        for (int q = 0; q < 4; ++q) {
            int idx = 4 * t + q;
            c[q] = (idx < NCTR) ? st_cnt[idx] : 0u;
            sum += c[q];
        }
        unsigned inc = sum;
#pragma unroll
        for (int off = 1; off < 64; off <<= 1) {
            unsigned v = (unsigned)__shfl_up((int)inc, off, 64);
            if (lane >= off) inc += v;
        }
        if (lane == 63) wsum[wv] = inc;
        __syncthreads();
        if (t == 0) {
            unsigned run = 0;
#pragma unroll
            for (int w = 0; w < NCOPY; ++w) { unsigned tmp = wsum[w]; wsum[w] = run; run += tmp; }
        }
        __syncthreads();
        unsigned base = wsum[wv] + inc - sum;
#pragma unroll
        for (int q = 0; q < 4; ++q) {
            int idx = 4 * t + q;
            if (idx < NCTR) st_start[idx] = base;
            base += c[q];
        }
    }
    __syncthreads();

#pragma unroll
    for (int j = 0; j < EPT; ++j) {
        if (hcr[j] != INVALID) {
            unsigned cidx = hcr[j] >> 10, r = hcr[j] & 0x3FFu;
            stage[st_start[cidx] + r] = held[j];
        }
    }

    if (t <= NBK)
        offs[(size_t)blockIdx.x * ROWS + t] =
            (unsigned short)((t == NBK) ? EPB : st_start[t * NCOPY]);
    __syncthreads();

    const uint4* sg = (const uint4*)stage;
    uint4* pg = (uint4*)(part + (size_t)blockIdx.x * EPB);
    for (int j = t; j < EPB / 4; j += PTH) pg[j] = sg[j];
}

// ---------------------------------------------------------------------------
// Kernel 3: accumulate — batched-ILP version. 784 blocks x 512 thr (SPLIT=4,
// one region/thread, one node/thread).
//  Pass A: region run read via ALIGNED uint4 window (3 independent dwordx4,
//          12 compile-time slots + validity masks) -> one latency round.
//  Scan:   node counts padded to 4-aligned starts.
//  Pass C: 2 independent ds_read_b128 + 8 independent masked z-gathers ->
//          one latency round instead of deg sequential rounds.
// ---------------------------------------------------------------------------
__global__ __launch_bounds__(ATH) void acc_kernel(
    const unsigned short* __restrict__ offs, const unsigned* __restrict__ part,
    const unsigned* __restrict__ zb, float* __restrict__ partial)
{
    __shared__ unsigned s_cnt[512];
    __shared__ unsigned s_start[512];
    __shared__ __align__(16) unsigned sstage[SCAP + 8];
    __shared__ unsigned ovf[2 * OVCAP];
    __shared__ unsigned novf;
    __shared__ unsigned wtot[8];

    const int t    = threadIdx.x;
    const int lane = t & 63;
    const int k    = blockIdx.x >> 2;      // bucket
    const int sp   = blockIdx.x & 3;       // split

    s_cnt[t] = 0;
    if (t == 0) novf = 0;
    __syncthreads();

    unsigned rbase = 0, len = 0;
    if (t < RPS) {
        unsigned r = (unsigned)(sp * RPS + t);
        unsigned o0 = offs[(size_t)r * ROWS + k];
        unsigned o1 = offs[(size_t)r * ROWS + k + 1];
        len   = o1 - o0;
        rbase = r * EPB + o0;
    }

    // ---- pass A: aligned-window vector read + merged hist+rank ----
    unsigned sh = rbase & 3u;
    const uint4* p4 = (const uint4*)part;
    unsigned wbase = rbase >> 2;
    // 3 independent 16B loads (slack allocated past part[NE])
    uint4 W0 = len ? p4[wbase]     : make_uint4(0, 0, 0, 0);
    uint4 W1 = len ? p4[wbase + 1] : make_uint4(0, 0, 0, 0);
    uint4 W2 = len ? p4[wbase + 2] : make_uint4(0, 0, 0, 0);
    unsigned win[WSLOT] = {W0.x, W0.y, W0.z, W0.w,
                           W1.x, W1.y, W1.z, W1.w,
                           W2.x, W2.y, W2.z, W2.w};
    unsigned hsrc[WSLOT], hnr[WSLOT];
    unsigned F = min(len, WSLOT - sh);     // fast-path edge count (>=9)
#pragma unroll
    for (int q = 0; q < WSLOT; ++q) {
        unsigned uq = (unsigned)q;
        if (uq >= sh && uq < sh + F) {
            unsigned e = win[q];
            unsigned node = e >> 17;
            unsigned rk = atomicAdd(&s_cnt[node], 1u);
            hsrc[q] = e & 0x1FFFFu;
            hnr[q]  = (node << 16) | rk;
        } else hnr[q] = INVALID;
    }
    for (unsigned j = F; j < len; ++j) {   // rare tail (P~1% of regions)
        unsigned e = part[rbase + j];
        unsigned node = e >> 17;
        unsigned rk = atomicAdd(&s_cnt[node], 1u);
        unsigned pp = atomicAdd(&novf, 1u);
        if (pp < OVCAP) {
            ovf[2 * pp]     = (node << 16) | rk;
            ovf[2 * pp + 1] = e & 0x1FFFFu;
        }
    }
    __syncthreads();

    // ---- shfl-scan of 512 node counts, starts padded to 4-aligned ----
    unsigned cval = s_cnt[t];
    unsigned pcnt = (cval + 3u) & ~3u;     // padded count keeps starts aligned
    unsigned inc = pcnt;
#pragma unroll
    for (int off = 1; off < 64; off <<= 1) {
        unsigned v = (unsigned)__shfl_up((int)inc, off, 64);
        if (lane >= off) inc += v;
    }
    if (lane == 63) wtot[t >> 6] = inc;
    __syncthreads();
    if (t == 0) {
        unsigned run = 0;
#pragma unroll
        for (int w = 0; w < 8; ++w) { unsigned tmp = wtot[w]; wtot[w] = run; run += tmp; }
    }
    __syncthreads();
    unsigned mybase = wtot[t >> 6] + inc - pcnt;
    s_start[t] = mybase;
    __syncthreads();

    // ---- pass B: scatter from registers (+ overflow) node-sorted ----
#pragma unroll
    for (int q = 0; q < WSLOT; ++q) {
        if (hnr[q] != INVALID) {
            unsigned node = hnr[q] >> 16, rk = hnr[q] & 0xffffu;
            unsigned pp = s_start[node] + rk;
            if (pp < SCAP) sstage[pp] = hsrc[q];
        }
    }
    for (unsigned q = t; q < min(novf, (unsigned)OVCAP); q += ATH) {
        unsigned nr = ovf[2 * q], src = ovf[2 * q + 1];
        unsigned pp = s_start[nr >> 16] + (nr & 0xffffu);
        if (pp < SCAP) sstage[pp] = src;
    }
    __syncthreads();

    // ---- pass C: batched reduce of node t's run (deg ~Poisson(4)) ----
    unsigned deg = s_cnt[t];
    // 2 independent b128 LDS reads cover first 8 srcs (aligned base)
    uint4 C0 = *(const uint4*)&sstage[mybase];
    uint4 C1 = *(const uint4*)&sstage[mybase + 4];
    unsigned sv[8] = {C0.x, C0.y, C0.z, C0.w, C1.x, C1.y, C1.z, C1.w};

    float a0 = 0.f, a1 = 0.f, a2 = 0.f, a3 = 0.f, a4 = 0.f, a5 = 0.f, a6 = 0.f;
#pragma unroll
    for (int j = 0; j < 8; ++j) {
        // masked independent gathers: all 8 issue before one waitcnt
        unsigned src = ((unsigned)j < deg) ? sv[j] : 0u;
        float m = ((unsigned)j < deg) ? 1.0f : 0.0f;
        uint4 zr = ((const uint4*)zb)[src];
        a0 = fmaf(m, bflo(zr.x), a0); a1 = fmaf(m, bfhi(zr.x), a1);
        a2 = fmaf(m, bflo(zr.y), a2); a3 = fmaf(m, bfhi(zr.y), a3);
        a4 = fmaf(m, bflo(zr.z), a4); a5 = fmaf(m, bfhi(zr.z), a5);
        a6 = fmaf(m, bflo(zr.w), a6);
    }
    for (unsigned j = 8; j < deg; ++j) {   // tail (P(deg>8)~2%)
        unsigned pp = mybase + j;
        if (pp >= SCAP) break;
        uint4 zr = ((const uint4*)zb)[sstage[pp]];
        a0 += bflo(zr.x); a1 += bfhi(zr.x);
        a2 += bflo(zr.y); a3 += bfhi(zr.y);
        a4 += bflo(zr.z); a5 += bfhi(zr.z);
        a6 += bflo(zr.w);
    }

    float* pp = partial + ((size_t)blockIdx.x * 512 + t) * 8;
    *(float4*)(pp)     = make_float4(a0, a1, a2, a3);
    *(float4*)(pp + 4) = make_float4(a4, a5, a6, (float)deg);
}

// ---------------------------------------------------------------------------
// Kernel 4: merge 4 split partials + mean + self + relu.
// ---------------------------------------------------------------------------
__global__ __launch_bounds__(256) void merge_kernel(
    const float* __restrict__ partial, float* __restrict__ out, int n)
{
    int i = blockIdx.x * blockDim.x + threadIdx.x;
    if (i >= n) return;
    int k = i >> BSH;
    int node = i & 511;

    float s0 = 0.f, s1 = 0.f, s2 = 0.f, s3 = 0.f, s4 = 0.f, s5 = 0.f, s6 = 0.f, cn = 0.f;
#pragma unroll
    for (int s = 0; s < SPLIT; ++s) {
        const float4* p = (const float4*)(partial + ((size_t)(k * SPLIT + s) * 512 + node) * 8);
        float4 a = p[0], b = p[1];
        s0 += a.x; s1 += a.y; s2 += a.z; s3 += a.w;
        s4 += b.x; s5 += b.y; s6 += b.z; cn += b.w;
    }
    float r = 1.0f / fmaxf(cn, 1.0f);
    float* o = out + (size_t)i * FOUT;
    o[0] = fmaxf(fmaf(s0, r, o[0]), 0.f);
    o[1] = fmaxf(fmaf(s1, r, o[1]), 0.f);
    o[2] = fmaxf(fmaf(s2, r, o[2]), 0.f);
    o[3] = fmaxf(fmaf(s3, r, o[3]), 0.f);
    o[4] = fmaxf(fmaf(s4, r, o[4]), 0.f);
    o[5] = fmaxf(fmaf(s5, r, o[5]), 0.f);
    o[6] = fmaxf(fmaf(s6, r, o[6]), 0.f);
}

extern "C" void kernel_launch(void* const* d_in, const int* in_sizes, int n_in,
                              void* d_out, int out_size, void* d_ws, size_t ws_size,
                              hipStream_t stream) {
    const float* x   = (const float*)d_in[0];
    const int*   edg = (const int*)d_in[1];    // harness passes integers as int32
    const float* Wl  = (const float*)d_in[2];
    const float* bl  = (const float*)d_in[3];
    const float* Wr  = (const float*)d_in[4];
    float* out = (float*)d_out;

    // ws: z 1.6 MB | part 6.4 MB (+64B window slack) | offs 0.8 MB | partial 12.9 MB
    unsigned*       z       = (unsigned*)d_ws;                            // [NN*4]
    unsigned*       part    = z + (size_t)NN * 4;                         // [NE + 16]
    unsigned short* offs    = (unsigned short*)(part + (size_t)NE + 16); // [PBLK*ROWS]
    float*          partial = (float*)(offs + (size_t)PBLK * ROWS);      // [NTASK*512*8]

    proj_kernel<<<PROJB, 256, 0, stream>>>(x, Wl, bl, Wr, z, out, NN);
    part_kernel<<<PBLK, PTH, 0, stream>>>(edg, part, offs);
    acc_kernel<<<NTASK, ATH, 0, stream>>>(offs, part, z, partial);
    merge_kernel<<<(NN + 255) / 256, 256, 0, stream>>>(partial, out, NN);
}

// Round 15
// 120.577 us; speedup vs baseline: 2.5244x; 1.0233x over previous
//
#include <hip/hip_runtime.h>

#define NN 100000
#define NE 1600000
#define FIN 64
#define FOUT 7

#define BSH 9                        // bucket = dst >> 9 (512 nodes)
#define NBK 196                      // ceil(100000/512)
#define PBLK 2000                    // partition blocks (2000*800 = NE exact)
#define PTH  256
#define EPB  800                     // edges per partition region
#define NCOPY 4                      // per-wave counter copies (4 waves)
#define NCTR (NBK * NCOPY)           // 784
#define ROWS 200                     // offs row stride in u16 (197 used)
#define SPLIT 4                      // acc blocks per bucket
#define NTASK (NBK * SPLIT)          // 784
#define RPS (PBLK / SPLIT)           // 500 regions per acc task
#define ATH 512
#define WSLOT 12                     // aligned uint4 window: 3 x dwordx4
#define OVCAP 256                    // LDS overflow pairs (expect ~20/task)
#define SCAP 3968                    // padded stage cap (edges<=2250 + align pad 1536)
#define PROJB 391
#define INVALID 0xFFFFFFFFu

__device__ __forceinline__ unsigned bf16r(float f) {   // round-to-nearest-even
    unsigned u = __float_as_uint(f);
    return (u + 0x7fffu + ((u >> 16) & 1u)) >> 16;
}
__device__ __forceinline__ float bflo(unsigned u) { return __uint_as_float(u << 16); }
__device__ __forceinline__ float bfhi(unsigned u) { return __uint_as_float(u & 0xffff0000u); }

// ---------------------------------------------------------------------------
// Kernel 1: per-node projections (R10-identical).
// ---------------------------------------------------------------------------
__global__ __launch_bounds__(256) void proj_kernel(
    const float* __restrict__ x, const float* __restrict__ Wl,
    const float* __restrict__ bl, const float* __restrict__ Wr,
    unsigned* __restrict__ z, float* __restrict__ outself, int n)
{
    int i = blockIdx.x * blockDim.x + threadIdx.x;
    if (i >= n) return;

    float al[FOUT], ar[FOUT];
#pragma unroll
    for (int j = 0; j < FOUT; ++j) { al[j] = 0.f; ar[j] = 0.f; }

    const float4* xr = (const float4*)(x + (size_t)i * FIN);
#pragma unroll
    for (int kk = 0; kk < FIN / 4; ++kk) {
        float4 xv = xr[kk];
        float v[4] = {xv.x, xv.y, xv.z, xv.w};
#pragma unroll
        for (int c = 0; c < 4; ++c) {
            int k = kk * 4 + c;
#pragma unroll
            for (int j = 0; j < FOUT; ++j) {
                al[j] = fmaf(v[c], Wl[k * FOUT + j], al[j]);   // uniform -> s_load
                ar[j] = fmaf(v[c], Wr[k * FOUT + j], ar[j]);
            }
        }
    }

    uint4 pk;
    pk.x = bf16r(al[0]) | (bf16r(al[1]) << 16);
    pk.y = bf16r(al[2]) | (bf16r(al[3]) << 16);
    pk.z = bf16r(al[4]) | (bf16r(al[5]) << 16);
    pk.w = bf16r(al[6]);
    ((uint4*)z)[i] = pk;

    float* o = outself + (size_t)i * FOUT;
#pragma unroll
    for (int j = 0; j < FOUT; ++j)
        o[j] = ar[j] + bl[j];
}

// ---------------------------------------------------------------------------
// Kernel 2: partition — pass-A efficiency fixes (single-kernel change):
//  (a) edge loads vectorized: thread t<200 reads 4 srcs + 4 dsts as two
//      independent dwordx4 (16B-aligned: e0=blk*800, 800%4==0).
//  (b) counter layout copy-major: cidx = wv*NBK + b -> within a wave the
//      ds_atomic_ret walks consecutive banks (~2-way, free) instead of the
//      old bucket-major 16B stride that hit only 8/32 banks (8-way serial).
//  Scan restructured: per-bucket sum of the 4 wave-copies + 196-entry shfl
//  scan -> bucket starts (offs) + per-(wave,bucket) starts for pass B.
// ---------------------------------------------------------------------------
__global__ __launch_bounds__(PTH) void part_kernel(
    const int* __restrict__ eg, unsigned* __restrict__ part,
    unsigned short* __restrict__ offs)
{
    __shared__ unsigned st_cnt[NCTR];      // copy-major: [wave][bucket]
    __shared__ unsigned st_start[NCTR];
    __shared__ unsigned stage[EPB];
    __shared__ unsigned wsum[NCOPY];

    const int t    = threadIdx.x;
    const int e0   = (int)blockIdx.x * EPB;
    const int lane = t & 63;
    const int wv   = t >> 6;

    for (int b = t; b < NCTR; b += PTH) st_cnt[b] = 0;
    __syncthreads();

    // pass A: two dwordx4 edge loads + merged hist+rank on this wave's copy
    unsigned held[4], hcr[4];
#pragma unroll
    for (int q = 0; q < 4; ++q) hcr[q] = INVALID;
    if (t < EPB / 4) {
        uint4 S = *(const uint4*)(eg + e0 + 4 * t);        // 4 srcs
        uint4 D = *(const uint4*)(eg + NE + e0 + 4 * t);   // 4 dsts
        unsigned ss[4] = {S.x, S.y, S.z, S.w};
        unsigned dd[4] = {D.x, D.y, D.z, D.w};
#pragma unroll
        for (int q = 0; q < 4; ++q) {
            unsigned b = dd[q] >> BSH;
            unsigned cidx = (unsigned)wv * NBK + b;        // copy-major
            unsigned r = atomicAdd(&st_cnt[cidx], 1u);
            held[q] = ((dd[q] & 511u) << 17) | ss[q];      // ldst 9b | src 17b
            hcr[q]  = (cidx << 10) | r;                    // cidx 10b | r<800 10b
        }
    }
    __syncthreads();

    // scan: thread t<196 owns bucket t; sum its 4 wave-copies, then a
    // 196-entry shfl scan across 4 waves for bucket starts.
    unsigned c[4], p[4], tot = 0;
    if (t < NBK) {
#pragma unroll
        for (int w = 0; w < NCOPY; ++w) c[w] = st_cnt[w * NBK + t];
        p[0] = 0; p[1] = c[0]; p[2] = c[0] + c[1]; p[3] = p[2] + c[2];
        tot = p[3] + c[3];
    }
    unsigned inc = tot;
#pragma unroll
    for (int off = 1; off < 64; off <<= 1) {
        unsigned v = (unsigned)__shfl_up((int)inc, off, 64);
        if (lane >= off) inc += v;
    }
    if (lane == 63) wsum[wv] = inc;
    __syncthreads();
    if (t == 0) {
        unsigned run = 0;
#pragma unroll
        for (int w = 0; w < NCOPY; ++w) { unsigned tmp = wsum[w]; wsum[w] = run; run += tmp; }
    }
    __syncthreads();
    unsigned bstart = wsum[wv] + inc - tot;    // exclusive bucket start
    if (t < NBK) {
        offs[(size_t)blockIdx.x * ROWS + t] = (unsigned short)bstart;
#pragma unroll
        for (int w = 0; w < NCOPY; ++w) st_start[w * NBK + t] = bstart + p[w];
    }
    if (t == NBK) offs[(size_t)blockIdx.x * ROWS + NBK] = (unsigned short)EPB;
    __syncthreads();

    // pass B: place held edges into bucket-sorted stage
#pragma unroll
    for (int q = 0; q < 4; ++q) {
        if (hcr[q] != INVALID) {
            unsigned cidx = hcr[q] >> 10, r = hcr[q] & 0x3FFu;
            stage[st_start[cidx] + r] = held[q];
        }
    }
    __syncthreads();

    // pass C: linear region dump (uint4)
    const uint4* sg = (const uint4*)stage;
    uint4* pg = (uint4*)(part + (size_t)blockIdx.x * EPB);
    for (int j = t; j < EPB / 4; j += PTH) pg[j] = sg[j];
}

// ---------------------------------------------------------------------------
// Kernel 3: accumulate (R14-identical): batched-ILP, 784 blocks x 512 thr.
// ---------------------------------------------------------------------------
__global__ __launch_bounds__(ATH) void acc_kernel(
    const unsigned short* __restrict__ offs, const unsigned* __restrict__ part,
    const unsigned* __restrict__ zb, float* __restrict__ partial)
{
    __shared__ unsigned s_cnt[512];
    __shared__ unsigned s_start[512];
    __shared__ __align__(16) unsigned sstage[SCAP + 8];
    __shared__ unsigned ovf[2 * OVCAP];
    __shared__ unsigned novf;
    __shared__ unsigned wtot[8];

    const int t    = threadIdx.x;
    const int lane = t & 63;
    const int k    = blockIdx.x >> 2;      // bucket
    const int sp   = blockIdx.x & 3;       // split

    s_cnt[t] = 0;
    if (t == 0) novf = 0;
    __syncthreads();

    unsigned rbase = 0, len = 0;
    if (t < RPS) {
        unsigned r = (unsigned)(sp * RPS + t);
        unsigned o0 = offs[(size_t)r * ROWS + k];
        unsigned o1 = offs[(size_t)r * ROWS + k + 1];
        len   = o1 - o0;
        rbase = r * EPB + o0;
    }

    // ---- pass A: aligned-window vector read + merged hist+rank ----
    unsigned sh = rbase & 3u;
    const uint4* p4 = (const uint4*)part;
    unsigned wbase = rbase >> 2;
    uint4 W0 = len ? p4[wbase]     : make_uint4(0, 0, 0, 0);
    uint4 W1 = len ? p4[wbase + 1] : make_uint4(0, 0, 0, 0);
    uint4 W2 = len ? p4[wbase + 2] : make_uint4(0, 0, 0, 0);
    unsigned win[WSLOT] = {W0.x, W0.y, W0.z, W0.w,
                           W1.x, W1.y, W1.z, W1.w,
                           W2.x, W2.y, W2.z, W2.w};
    unsigned hsrc[WSLOT], hnr[WSLOT];
    unsigned F = min(len, WSLOT - sh);
#pragma unroll
    for (int q = 0; q < WSLOT; ++q) {
        unsigned uq = (unsigned)q;
        if (uq >= sh && uq < sh + F) {
            unsigned e = win[q];
            unsigned node = e >> 17;
            unsigned rk = atomicAdd(&s_cnt[node], 1u);
            hsrc[q] = e & 0x1FFFFu;
            hnr[q]  = (node << 16) | rk;
        } else hnr[q] = INVALID;
    }
    for (unsigned j = F; j < len; ++j) {   // rare tail
        unsigned e = part[rbase + j];
        unsigned node = e >> 17;
        unsigned rk = atomicAdd(&s_cnt[node], 1u);
        unsigned pp = atomicAdd(&novf, 1u);
        if (pp < OVCAP) {
            ovf[2 * pp]     = (node << 16) | rk;
            ovf[2 * pp + 1] = e & 0x1FFFFu;
        }
    }
    __syncthreads();

    // ---- shfl-scan of 512 node counts, starts padded to 4-aligned ----
    unsigned cval = s_cnt[t];
    unsigned pcnt = (cval + 3u) & ~3u;
    unsigned inc = pcnt;
#pragma unroll
    for (int off = 1; off < 64; off <<= 1) {
        unsigned v = (unsigned)__shfl_up((int)inc, off, 64);
        if (lane >= off) inc += v;
    }
    if (lane == 63) wtot[t >> 6] = inc;
    __syncthreads();
    if (t == 0) {
        unsigned run = 0;
#pragma unroll
        for (int w = 0; w < 8; ++w) { unsigned tmp = wtot[w]; wtot[w] = run; run += tmp; }
    }
    __syncthreads();
    unsigned mybase = wtot[t >> 6] + inc - pcnt;
    s_start[t] = mybase;
    __syncthreads();

    // ---- pass B: scatter from registers (+ overflow) node-sorted ----
#pragma unroll
    for (int q = 0; q < WSLOT; ++q) {
        if (hnr[q] != INVALID) {
            unsigned node = hnr[q] >> 16, rk = hnr[q] & 0xffffu;
            unsigned pp = s_start[node] + rk;
            if (pp < SCAP) sstage[pp] = hsrc[q];
        }
    }
    for (unsigned q = t; q < min(novf, (unsigned)OVCAP); q += ATH) {
        unsigned nr = ovf[2 * q], src = ovf[2 * q + 1];
        unsigned pp = s_start[nr >> 16] + (nr & 0xffffu);
        if (pp < SCAP) sstage[pp] = src;
    }
    __syncthreads();

    // ---- pass C: batched reduce of node t's run ----
    unsigned deg = s_cnt[t];
    uint4 C0 = *(const uint4*)&sstage[mybase];
    uint4 C1 = *(const uint4*)&sstage[mybase + 4];
    unsigned sv[8] = {C0.x, C0.y, C0.z, C0.w, C1.x, C1.y, C1.z, C1.w};

    float a0 = 0.f, a1 = 0.f, a2 = 0.f, a3 = 0.f, a4 = 0.f, a5 = 0.f, a6 = 0.f;
#pragma unroll
    for (int j = 0; j < 8; ++j) {
        unsigned src = ((unsigned)j < deg) ? sv[j] : 0u;
        float m = ((unsigned)j < deg) ? 1.0f : 0.0f;
        uint4 zr = ((const uint4*)zb)[src];
        a0 = fmaf(m, bflo(zr.x), a0); a1 = fmaf(m, bfhi(zr.x), a1);
        a2 = fmaf(m, bflo(zr.y), a2); a3 = fmaf(m, bfhi(zr.y), a3);
        a4 = fmaf(m, bflo(zr.z), a4); a5 = fmaf(m, bfhi(zr.z), a5);
        a6 = fmaf(m, bflo(zr.w), a6);
    }
    for (unsigned j = 8; j < deg; ++j) {   // tail
        unsigned pp = mybase + j;
        if (pp >= SCAP) break;
        uint4 zr = ((const uint4*)zb)[sstage[pp]];
        a0 += bflo(zr.x); a1 += bfhi(zr.x);
        a2 += bflo(zr.y); a3 += bfhi(zr.y);
        a4 += bflo(zr.z); a5 += bfhi(zr.z);
        a6 += bflo(zr.w);
    }

    float* pp = partial + ((size_t)blockIdx.x * 512 + t) * 8;
    *(float4*)(pp)     = make_float4(a0, a1, a2, a3);
    *(float4*)(pp + 4) = make_float4(a4, a5, a6, (float)deg);
}

// ---------------------------------------------------------------------------
// Kernel 4: merge 4 split partials + mean + self + relu.
// ---------------------------------------------------------------------------
__global__ __launch_bounds__(256) void merge_kernel(
    const float* __restrict__ partial, float* __restrict__ out, int n)
{
    int i = blockIdx.x * blockDim.x + threadIdx.x;
    if (i >= n) return;
    int k = i >> BSH;
    int node = i & 511;

    float s0 = 0.f, s1 = 0.f, s2 = 0.f, s3 = 0.f, s4 = 0.f, s5 = 0.f, s6 = 0.f, cn = 0.f;
#pragma unroll
    for (int s = 0; s < SPLIT; ++s) {
        const float4* p = (const float4*)(partial + ((size_t)(k * SPLIT + s) * 512 + node) * 8);
        float4 a = p[0], b = p[1];
        s0 += a.x; s1 += a.y; s2 += a.z; s3 += a.w;
        s4 += b.x; s5 += b.y; s6 += b.z; cn += b.w;
    }
    float r = 1.0f / fmaxf(cn, 1.0f);
    float* o = out + (size_t)i * FOUT;
    o[0] = fmaxf(fmaf(s0, r, o[0]), 0.f);
    o[1] = fmaxf(fmaf(s1, r, o[1]), 0.f);
    o[2] = fmaxf(fmaf(s2, r, o[2]), 0.f);
    o[3] = fmaxf(fmaf(s3, r, o[3]), 0.f);
    o[4] = fmaxf(fmaf(s4, r, o[4]), 0.f);
    o[5] = fmaxf(fmaf(s5, r, o[5]), 0.f);
    o[6] = fmaxf(fmaf(s6, r, o[6]), 0.f);
}

extern "C" void kernel_launch(void* const* d_in, const int* in_sizes, int n_in,
                              void* d_out, int out_size, void* d_ws, size_t ws_size,
                              hipStream_t stream) {
    const float* x   = (const float*)d_in[0];
    const int*   edg = (const int*)d_in[1];    // harness passes integers as int32
    const float* Wl  = (const float*)d_in[2];
    const float* bl  = (const float*)d_in[3];
    const float* Wr  = (const float*)d_in[4];
    float* out = (float*)d_out;

    // ws: z 1.6 MB | part 6.4 MB (+64B window slack) | offs 0.8 MB | partial 12.9 MB
    unsigned*       z       = (unsigned*)d_ws;                            // [NN*4]
    unsigned*       part    = z + (size_t)NN * 4;                         // [NE + 16]
    unsigned short* offs    = (unsigned short*)(part + (size_t)NE + 16); // [PBLK*ROWS]
    float*          partial = (float*)(offs + (size_t)PBLK * ROWS);      // [NTASK*512*8]

    proj_kernel<<<PROJB, 256, 0, stream>>>(x, Wl, bl, Wr, z, out, NN);
    part_kernel<<<PBLK, PTH, 0, stream>>>(edg, part, offs);
    acc_kernel<<<NTASK, ATH, 0, stream>>>(offs, part, z, partial);
    merge_kernel<<<(NN + 255) / 256, 256, 0, stream>>>(partial, out, NN);
}